// Round 11
// baseline (210.292 us; speedup 1.0000x reference)
//
#include <hip/hip_runtime.h>
#include <hip/hip_bf16.h>

constexpr int B_ = 4;
constexpr int L_ = 2048;
constexpr int D_ = 256;
constexpr int P_ = 32;
constexpr int CL = 32;
constexpr int NC = L_ / CL;  // 64

#define PI_F 3.14159265358979323846f
#define INV_SQRT_P 0.17677669529663687f

typedef __attribute__((ext_vector_type(8))) short short8_t;
typedef __attribute__((ext_vector_type(4))) float floatx4;

static __device__ inline short f2bf(float f) {
  unsigned int u;
  __builtin_memcpy(&u, &f, 4);
  unsigned int r = (u + 0x7fffu + ((u >> 16) & 1u)) >> 16;
  return (short)r;
}
static __device__ inline float bf2f(short s) {
  unsigned int u = ((unsigned int)(unsigned short)s) << 16;
  float f;
  __builtin_memcpy(&f, &u, 4);
  return f;
}

// A-fragment (lane holds A[m][k0..k0+7]) from fp32 row-major [m][256].
static __device__ inline short8_t loadAfragF32(const float* __restrict__ X,
                                               int row, int k0) {
  float4 v0 = *(const float4*)&X[row * 256 + k0];
  float4 v1 = *(const float4*)&X[row * 256 + k0 + 4];
  short s[8] = {f2bf(v0.x), f2bf(v0.y), f2bf(v0.z), f2bf(v0.w),
                f2bf(v1.x), f2bf(v1.y), f2bf(v1.z), f2bf(v1.w)};
  return *(short8_t*)s;
}

// ---------------- wprep: bf16 [n][k] weight transposes only ----------------
__global__ void wprep(const float* __restrict__ w_val, const float* __restrict__ w_mem1v,
                      const float* __restrict__ w_off, const float* __restrict__ w_key,
                      const float* __restrict__ w_gate, const float* __restrict__ w_sk1,
                      const float* __restrict__ w_out, const float* __restrict__ w_sk2,
                      const float* __restrict__ w_mem1o,
                      short* __restrict__ WAT, short* __restrict__ W1T,
                      short* __restrict__ WOT, short* __restrict__ W2T,
                      short* __restrict__ W1OT) {
  int blk = blockIdx.x, tid = threadIdx.x;
  if (blk < 384) {
    int idx = blk * 256 + tid;  // n*256 + k, n < 384
    int n = idx >> 8, k = idx & 255;
    float v;
    if (n < 256) v = w_val[k * 256 + n];
    else if (n < 288) v = w_mem1v[k * 32 + (n - 256)];
    else if (n < 320) v = w_off[k * 32 + (n - 288)];
    else if (n < 352) v = w_key[k * 32 + (n - 320)];
    else if (n == 352) v = w_gate[k];
    else v = 0.f;
    WAT[idx] = f2bf(v);
  } else if (blk < 896) {
    int idx = (blk - 384) * 256 + tid;  // n*512 + k
    int n = idx >> 9, k = idx & 511;
    W1T[idx] = f2bf(w_sk1[k * 256 + n]);
  } else if (blk < 1152) {
    int idx = (blk - 896) * 256 + tid;  // n*256 + k
    int n = idx >> 8, k = idx & 255;
    WOT[idx] = f2bf(w_out[k * 256 + n]);
  } else if (blk < 1184) {
    int idx = (blk - 1152) * 256 + tid;  // p*256 + k
    int p = idx >> 8, k = idx & 255;
    W2T[idx] = f2bf(w_sk2[k * 32 + p]);
  } else {
    int idx = (blk - 1184) * 256 + tid;  // d*32 + p
    int d = idx >> 5, p = idx & 31;
    W1OT[idx] = f2bf(w_mem1o[p * 256 + d]);
  }
}

// ---------------- Kernel A3G: gemm0 + phasor prep + ctx half-chunk sums ----
// Block = 16 tokens (half chunk). Y kept in LDS fp32, never global.
__global__ __launch_bounds__(256) void kernelA3G(
    const float* __restrict__ x, const float* __restrict__ pos,
    const short* __restrict__ WAT, const float* __restrict__ w_off,
    const float* __restrict__ b_mem1v, const float* __restrict__ b_off,
    const float* __restrict__ b_key, const float* __restrict__ b_gate,
    const float* __restrict__ b_val,
    float* __restrict__ m1cT, float* __restrict__ m1sT,
    float* __restrict__ qc, float* __restrict__ qs,
    short* __restrict__ K2bf, short* __restrict__ gvT,
    float* __restrict__ sg, float* __restrict__ ctxsum) {
  __shared__ float Yl[16][390];  // ~25 KB
  __shared__ float gsh[16];
  int tid = threadIdx.x;
  int blk = blockIdx.x;
  int lbase = blk * 16;  // global token base
  int b = lbase >> 11;
  int lane = tid & 63, w = tid >> 6;
  int ml = lane & 15, quad = lane >> 4, kq = quad * 8;

  // ---- Phase A: Y[16][384] = x @ WAT^T ----
  floatx4 acc[6] = {};
  const float* xrow = x + (size_t)lbase * 256;
  for (int ks = 0; ks < 8; ++ks) {
    int k0 = ks * 32 + kq;
    short8_t a0 = loadAfragF32(xrow, ml, k0);
#pragma unroll
    for (int nt = 0; nt < 6; ++nt) {
      int n = w * 96 + nt * 16;
      if (n > 352) continue;
      short8_t bfr = *(const short8_t*)&WAT[(n + ml) * 256 + k0];
      acc[nt] = __builtin_amdgcn_mfma_f32_16x16x32_bf16(a0, bfr, acc[nt], 0, 0, 0);
    }
  }
#pragma unroll
  for (int nt = 0; nt < 6; ++nt) {
    int n = w * 96 + nt * 16;
    if (n > 352) continue;
#pragma unroll
    for (int r = 0; r < 4; ++r) Yl[quad * 4 + r][n + ml] = acc[nt][r];
  }
  __syncthreads();

  // ---- Phase B: per-(t,p) phasor prep ----
  for (int h = 0; h < 2; ++h) {
    int t = h * 8 + (tid >> 5), p = tid & 31;
    int tok = lbase + t, l = tok & (L_ - 1);
    float gate = 1.f / (1.f + expf(-(Yl[t][352] + b_gate[0])));
    if (p == 0) {
      sg[tok] = gate;
      gsh[t] = gate;
    }
    float v1 = Yl[t][256 + p] + b_mem1v[p];
    float ph = pos[l * 32 + p];
    float pc = cosf(ph), ps = sinf(ph);
    m1cT[(b * 32 + p) * L_ + l] = pc * v1;
    m1sT[(b * 32 + p) * L_ + l] = ps * v1;
    float a = b_off[p];
    for (int j = 0; j < 32; ++j) a += pos[l * 32 + j] * w_off[(256 + j) * 32 + p];
    float off = tanhf(Yl[t][288 + p] + a) * PI_F;
    float oc = cosf(off), os = sinf(off);
    int idx = tok * 32 + p;
    qc[idx] = pc * oc - ps * os;
    qs[idx] = ps * oc + pc * os;
    float kp = tanhf(Yl[t][320 + p] + b_key[p]) * PI_F;
    K2bf[tok * 64 + p] = f2bf(cosf(kp));
    K2bf[tok * 64 + 32 + p] = f2bf(sinf(kp));
  }
  __syncthreads();

  // ---- Phase C: gvT (bf16, [d][t]) + ctx half-chunk sums ----
  {
    int d = tid;
    float bv = b_val[d];
    float cs = 0.f;
    short sv[16];
#pragma unroll 8
    for (int t = 0; t < 16; ++t) {
      cs += x[(size_t)(lbase + t) * 256 + d];
      sv[t] = f2bf((Yl[t][d] + bv) * gsh[t]);
    }
    int hc = (lbase & (L_ - 1)) >> 4;
    ctxsum[(b * 128 + hc) * 256 + d] = cs;
    int bc = lbase >> 5, tl0 = lbase & 31;
    int gb = (bc * 256 + d) * 32 + tl0;
    *(short8_t*)&gvT[gb] = *(short8_t*)&sv[0];
    *(short8_t*)&gvT[gb + 8] = *(short8_t*)&sv[8];
  }
}

// ---------------- scan_all: m1/sg scans + ctx local scan -------------------
// blk<256: m1 rows; 256..259: sg; 260..771: ctx half-chunk local scan.
__global__ void scan_all(float* __restrict__ m1cT, float* __restrict__ m1sT,
                         float* __restrict__ sg, const float* __restrict__ x,
                         const float* __restrict__ ctxsum, short* __restrict__ ctxbf) {
  int blk = blockIdx.x;
  int tid = threadIdx.x;
  if (blk >= 260) {
    int c2 = blk - 260;
    int b = c2 >> 7, hc = c2 & 127;
    float run = 0.f;
    int sb = b * 128 * 256 + tid;
    for (int c = 0; c < hc; ++c) run += ctxsum[sb + c * 256];
    int xb = (b * L_ + hc * 16) * 256 + tid;
#pragma unroll 8
    for (int i = 0; i < 16; ++i) {
      run += x[xb + i * 256];
      int l = hc * 16 + i;
      ctxbf[xb + i * 256] = f2bf(run / (float)(l + 1));
    }
    return;
  }
  int lane = tid & 63, wid = tid >> 6;
  __shared__ float wsum[4];
  float carry = 0.f;
  float* arr;
  int base;
  if (blk < 256) {
    arr = (blk < 128) ? m1cT : m1sT;
    base = (blk & 127) * L_;
  } else {
    arr = sg;
    base = (blk - 256) * L_;
  }
  for (int t0 = 0; t0 < L_; t0 += 256) {
    int l = t0 + tid;
    float v = arr[base + l];
#pragma unroll
    for (int off = 1; off < 64; off <<= 1) {
      float n = __shfl_up(v, off, 64);
      if (lane >= off) v += n;
    }
    if (lane == 63) wsum[wid] = v;
    __syncthreads();
    float add = carry;
    for (int w = 0; w < wid; ++w) add += wsum[w];
    arr[base + l] = v + add;
    carry += wsum[0] + wsum[1] + wsum[2] + wsum[3];
    __syncthreads();
  }
}

// ---------------- Kernel CDg: gemm1 (sk1) + sk2 phases + chunk U sums ------
__global__ __launch_bounds__(256) void kernelCDg(
    const float* __restrict__ x, const short* __restrict__ ctxbf,
    const short* __restrict__ W1T, const float* __restrict__ b_sk1,
    const short* __restrict__ W2T, const float* __restrict__ b_sk2,
    const short* __restrict__ gvT, short* __restrict__ SPbf,
    short* __restrict__ UT) {
  __shared__ __align__(16) short hsl[32][264];
  __shared__ __align__(16) short SPL[64][40];
  int tid = threadIdx.x;
  int bc = blockIdx.x;
  int lbase = bc * 32;
  int lane = tid & 63, w = tid >> 6;
  int ml = lane & 15, quad = lane >> 4, kq = quad * 8;

  // ---- Phase 1: hs = gelu([x|ctx] @ w_sk1 + b_sk1) ----
  floatx4 acc[2][4] = {};
  const float* xrow = x + (size_t)lbase * 256;
  for (int ks = 0; ks < 16; ++ks) {
    int k0 = ks * 32 + kq;
    short8_t a0, a1;
    if (ks < 8) {
      a0 = loadAfragF32(xrow, ml, k0);
      a1 = loadAfragF32(xrow, 16 + ml, k0);
    } else {
      a0 = *(const short8_t*)&ctxbf[(size_t)(lbase + ml) * 256 + (k0 - 256)];
      a1 = *(const short8_t*)&ctxbf[(size_t)(lbase + 16 + ml) * 256 + (k0 - 256)];
    }
#pragma unroll
    for (int nt = 0; nt < 4; ++nt) {
      short8_t bfr = *(const short8_t*)&W1T[(w * 64 + nt * 16 + ml) * 512 + k0];
      acc[0][nt] = __builtin_amdgcn_mfma_f32_16x16x32_bf16(a0, bfr, acc[0][nt], 0, 0, 0);
      acc[1][nt] = __builtin_amdgcn_mfma_f32_16x16x32_bf16(a1, bfr, acc[1][nt], 0, 0, 0);
    }
  }
#pragma unroll
  for (int nt = 0; nt < 4; ++nt) {
    int n = w * 64 + nt * 16 + ml;
    float bs = b_sk1[n];
#pragma unroll
    for (int mt = 0; mt < 2; ++mt)
#pragma unroll
      for (int r = 0; r < 4; ++r) {
        float v = acc[mt][nt][r] + bs;
        float g = 0.5f * v * (1.f + erff(v * 0.70710678118654752f));
        hsl[mt * 16 + quad * 4 + r][n] = f2bf(g);
      }
  }
  __syncthreads();

  // ---- Phase 2: storage phases (sk2) ----
  {
    int m0 = (w & 1) * 16, n0 = (w >> 1) * 16;
    floatx4 pacc = {};
#pragma unroll
    for (int ks = 0; ks < 8; ++ks) {
      int k0 = ks * 32 + kq;
      short8_t a = *(short8_t*)&hsl[m0 + ml][k0];
      short8_t bfr = *(const short8_t*)&W2T[(n0 + ml) * 256 + k0];
      pacc = __builtin_amdgcn_mfma_f32_16x16x32_bf16(a, bfr, pacc, 0, 0, 0);
    }
    int p = n0 + ml;
    float bs = b_sk2[p];
#pragma unroll
    for (int r = 0; r < 4; ++r) {
      int tl = m0 + quad * 4 + r;
      int tok = lbase + tl;
      float sp = tanhf(pacc[r] + bs) * PI_F;
      short c = f2bf(cosf(sp)), s = f2bf(sinf(sp));
      SPL[p][tl] = c;
      SPL[32 + p][tl] = s;
      SPbf[tok * 64 + p] = c;
      SPbf[tok * 64 + 32 + p] = s;
    }
  }
  __syncthreads();

  // ---- Phase 3: U_chunk[64 q][256 d] = SPL @ gv ----
  short8_t a[4];
#pragma unroll
  for (int mt = 0; mt < 4; ++mt) a[mt] = *(short8_t*)&SPL[mt * 16 + ml][kq];
  floatx4 uacc[4][4] = {};
#pragma unroll
  for (int nt = 0; nt < 4; ++nt) {
    short8_t bfr = *(const short8_t*)&gvT[(bc * 256 + w * 64 + nt * 16 + ml) * 32 + kq];
#pragma unroll
    for (int mt = 0; mt < 4; ++mt)
      uacc[mt][nt] = __builtin_amdgcn_mfma_f32_16x16x32_bf16(a[mt], bfr, uacc[mt][nt], 0, 0, 0);
  }
#pragma unroll
  for (int mt = 0; mt < 4; ++mt)
#pragma unroll
    for (int nt = 0; nt < 4; ++nt)
#pragma unroll
      for (int r = 0; r < 4; ++r) {
        int q = mt * 16 + quad * 4 + r;
        int d = w * 64 + nt * 16 + ml;
        UT[(bc * 256 + d) * 64 + q] = f2bf(uacc[mt][nt][r]);
      }
}

// ---------------- Kernel E: exclusive chunk prefix over UT (bf16) ----------
__global__ void kernelE(short* __restrict__ UT) {
  int gt = blockIdx.x * 256 + threadIdx.x;  // B*256d*64q = 65536
  int q = gt & 63;
  int d = (gt >> 6) & 255;
  int b = gt >> 14;
  int base = ((b * NC) * 256 + d) * 64 + q;
  const int cs = 256 * 64;
  float run = 0.f;
  for (int c0 = 0; c0 < NC; c0 += 8) {
    short v[8];
#pragma unroll
    for (int j = 0; j < 8; ++j) v[j] = UT[base + (c0 + j) * cs];
#pragma unroll
    for (int j = 0; j < 8; ++j) {
      UT[base + (c0 + j) * cs] = f2bf(run);
      run += bf2f(v[j]);
    }
  }
}

// ---------------- Kernel FGO: retrieval + pos_out + LN + output GEMM -------
__global__ __launch_bounds__(256) void kernelFGO(
    const short* __restrict__ UT, const short* __restrict__ SPbf,
    const short* __restrict__ K2bf, const short* __restrict__ gvT,
    const float* __restrict__ sgc, const float* __restrict__ m1cT,
    const float* __restrict__ m1sT, const float* __restrict__ qc,
    const float* __restrict__ qs, const short* __restrict__ W1OT,
    const float* __restrict__ b_mem1o, const float* __restrict__ ln_g,
    const float* __restrict__ ln_b, const float* __restrict__ x,
    const short* __restrict__ WOT, const float* __restrict__ b_out,
    float* __restrict__ out) {
  __shared__ __align__(16) short SL[32][40];
  __shared__ __align__(16) short PR[32][40];
  __shared__ float CMB[32][260];
  __shared__ __align__(16) short CBN[32][264];
  __shared__ float scl[32], mu_s[32], rs_s[32];
  int tid = threadIdx.x;
  int bc = blockIdx.x;
  int lbase = bc * CL;
  int bb = bc >> 6, lloc = (bc & 63) * 32;
  int lane = tid & 63, w = tid >> 6;
  int ml = lane & 15, quad = lane >> 4, kq = quad * 8;
  if (tid < 32) scl[tid] = rsqrtf(fmaxf(sgc[lbase + tid], 1.f)) * INV_SQRT_P;
  for (int it = 0; it < 4; ++it) {
    int i = it * 256 + tid;
    int p = i >> 5, t = i & 31;
    int gT = (bb * 32 + p) * L_ + lloc + t;
    int g = (lbase + t) * 32 + p;
    PR[t][p] = f2bf((m1cT[gT] * qc[g] + m1sT[gT] * qs[g]) * INV_SQRT_P);
  }
  floatx4 acc[2][4] = {};
  short8_t ka0 = *(const short8_t*)&K2bf[(lbase + ml) * 64 + kq];
  short8_t ka1 = *(const short8_t*)&K2bf[(lbase + 16 + ml) * 64 + kq];
  short8_t kb0 = *(const short8_t*)&K2bf[(lbase + ml) * 64 + 32 + kq];
  short8_t kb1 = *(const short8_t*)&K2bf[(lbase + 16 + ml) * 64 + 32 + kq];
#pragma unroll
  for (int nt = 0; nt < 4; ++nt) {
    short8_t b = *(const short8_t*)&UT[(bc * 256 + w * 64 + nt * 16 + ml) * 64 + kq];
    acc[0][nt] = __builtin_amdgcn_mfma_f32_16x16x32_bf16(ka0, b, acc[0][nt], 0, 0, 0);
    acc[1][nt] = __builtin_amdgcn_mfma_f32_16x16x32_bf16(ka1, b, acc[1][nt], 0, 0, 0);
  }
  if (w == 0) {
    floatx4 sacc[2][2] = {};
#pragma unroll
    for (int ks2 = 0; ks2 < 2; ++ks2) {
      short8_t a0 = (ks2 == 0) ? ka0 : kb0;
      short8_t a1 = (ks2 == 0) ? ka1 : kb1;
      short8_t b0 = *(const short8_t*)&SPbf[(lbase + ml) * 64 + ks2 * 32 + kq];
      short8_t b1 = *(const short8_t*)&SPbf[(lbase + 16 + ml) * 64 + ks2 * 32 + kq];
      sacc[0][0] = __builtin_amdgcn_mfma_f32_16x16x32_bf16(a0, b0, sacc[0][0], 0, 0, 0);
      sacc[0][1] = __builtin_amdgcn_mfma_f32_16x16x32_bf16(a0, b1, sacc[0][1], 0, 0, 0);
      sacc[1][0] = __builtin_amdgcn_mfma_f32_16x16x32_bf16(a1, b0, sacc[1][0], 0, 0, 0);
      sacc[1][1] = __builtin_amdgcn_mfma_f32_16x16x32_bf16(a1, b1, sacc[1][1], 0, 0, 0);
    }
#pragma unroll
    for (int mt = 0; mt < 2; ++mt)
#pragma unroll
      for (int nt = 0; nt < 2; ++nt)
#pragma unroll
        for (int r = 0; r < 4; ++r) {
          int trow = mt * 16 + quad * 4 + r;
          int scol = nt * 16 + ml;
          float v = (scol <= trow) ? sacc[mt][nt][r] : 0.f;
          SL[trow][scol] = f2bf(v);
        }
  }
  __syncthreads();
#pragma unroll
  for (int nt = 0; nt < 4; ++nt) {
    short8_t b = *(const short8_t*)&UT[(bc * 256 + w * 64 + nt * 16 + ml) * 64 + 32 + kq];
    acc[0][nt] = __builtin_amdgcn_mfma_f32_16x16x32_bf16(kb0, b, acc[0][nt], 0, 0, 0);
    acc[1][nt] = __builtin_amdgcn_mfma_f32_16x16x32_bf16(kb1, b, acc[1][nt], 0, 0, 0);
  }
  {
    short8_t a0 = *(short8_t*)&SL[ml][kq];
    short8_t a1 = *(short8_t*)&SL[16 + ml][kq];
#pragma unroll
    for (int nt = 0; nt < 4; ++nt) {
      short8_t b = *(const short8_t*)&gvT[(bc * 256 + w * 64 + nt * 16 + ml) * 32 + kq];
      acc[0][nt] = __builtin_amdgcn_mfma_f32_16x16x32_bf16(a0, b, acc[0][nt], 0, 0, 0);
      acc[1][nt] = __builtin_amdgcn_mfma_f32_16x16x32_bf16(a1, b, acc[1][nt], 0, 0, 0);
    }
  }
  floatx4 macc[2][4] = {};
  {
    short8_t a0 = *(short8_t*)&PR[ml][kq];
    short8_t a1 = *(short8_t*)&PR[16 + ml][kq];
#pragma unroll
    for (int nt = 0; nt < 4; ++nt) {
      short8_t b = *(const short8_t*)&W1OT[(w * 64 + nt * 16 + ml) * 32 + kq];
      macc[0][nt] = __builtin_amdgcn_mfma_f32_16x16x32_bf16(a0, b, macc[0][nt], 0, 0, 0);
      macc[1][nt] = __builtin_amdgcn_mfma_f32_16x16x32_bf16(a1, b, macc[1][nt], 0, 0, 0);
    }
  }
#pragma unroll
  for (int mt = 0; mt < 2; ++mt)
#pragma unroll
    for (int nt = 0; nt < 4; ++nt) {
      int d = w * 64 + nt * 16 + ml;
      float bm = b_mem1o[d];
#pragma unroll
      for (int r = 0; r < 4; ++r) {
        int t = mt * 16 + quad * 4 + r;
        CMB[t][d] = acc[mt][nt][r] * scl[t] + macc[mt][nt][r] + bm;
      }
    }
  __syncthreads();
  {
    int t = tid >> 3, g = tid & 7;
    float s = 0.f, s2 = 0.f;
#pragma unroll
    for (int j = 0; j < 32; ++j) {
      float v = CMB[t][g + j * 8];
      s += v;
      s2 += v * v;
    }
#pragma unroll
    for (int m = 1; m < 8; m <<= 1) {
      s += __shfl_xor(s, m, 64);
      s2 += __shfl_xor(s2, m, 64);
    }
    if (g == 0) {
      float mu = s / (float)D_;
      float var = s2 / (float)D_ - mu * mu;
      mu_s[t] = mu;
      rs_s[t] = rsqrtf(var + 1e-5f);
    }
  }
  __syncthreads();
  {
    float lg = ln_g[tid], lb = ln_b[tid];
#pragma unroll
    for (int t = 0; t < 32; ++t)
      CBN[t][tid] = f2bf((CMB[t][tid] - mu_s[t]) * rs_s[t] * lg + lb);
  }
  __syncthreads();
  // ---- output GEMM: out = x + CBN @ w_out + b_out ----
  floatx4 oacc[2][4] = {};
  for (int ks = 0; ks < 8; ++ks) {
    int k0 = ks * 32 + kq;
    short8_t a0 = *(short8_t*)&CBN[ml][k0];
    short8_t a1 = *(short8_t*)&CBN[16 + ml][k0];
#pragma unroll
    for (int nt = 0; nt < 4; ++nt) {
      short8_t b = *(const short8_t*)&WOT[(w * 64 + nt * 16 + ml) * 256 + k0];
      oacc[0][nt] = __builtin_amdgcn_mfma_f32_16x16x32_bf16(a0, b, oacc[0][nt], 0, 0, 0);
      oacc[1][nt] = __builtin_amdgcn_mfma_f32_16x16x32_bf16(a1, b, oacc[1][nt], 0, 0, 0);
    }
  }
#pragma unroll
  for (int nt = 0; nt < 4; ++nt) {
    int n = w * 64 + nt * 16 + ml;
    float bo = b_out[n];
#pragma unroll
    for (int mt = 0; mt < 2; ++mt)
#pragma unroll
      for (int r = 0; r < 4; ++r) {
        int tok = lbase + mt * 16 + quad * 4 + r;
        out[(size_t)tok * 256 + n] = x[(size_t)tok * 256 + n] + oacc[mt][nt][r] + bo;
      }
  }
}

extern "C" void kernel_launch(void* const* d_in, const int* in_sizes, int n_in,
                              void* d_out, int out_size, void* d_ws, size_t ws_size,
                              hipStream_t stream) {
  const float* x = (const float*)d_in[0];
  const float* pos = (const float*)d_in[1];
  const float* w_mem1v = (const float*)d_in[2];
  const float* b_mem1v = (const float*)d_in[3];
  const float* w_mem1o = (const float*)d_in[4];
  const float* b_mem1o = (const float*)d_in[5];
  const float* w_off = (const float*)d_in[6];
  const float* b_off = (const float*)d_in[7];
  const float* w_key = (const float*)d_in[8];
  const float* b_key = (const float*)d_in[9];
  const float* w_val = (const float*)d_in[10];
  const float* b_val = (const float*)d_in[11];
  const float* w_sk1 = (const float*)d_in[12];
  const float* b_sk1 = (const float*)d_in[13];
  const float* w_sk2 = (const float*)d_in[14];
  const float* b_sk2 = (const float*)d_in[15];
  const float* w_gate = (const float*)d_in[16];
  const float* b_gate = (const float*)d_in[17];
  const float* ln_g = (const float*)d_in[18];
  const float* ln_b = (const float*)d_in[19];
  const float* w_out = (const float*)d_in[20];
  const float* b_out = (const float*)d_in[21];
  float* out = (float*)d_out;
  float* ws = (float*)d_ws;

  const int BLP = B_ * L_ * P_;  // 262144
  const int BLD = B_ * L_ * D_;  // 2097152
  float* m1cT = ws;
  float* m1sT = m1cT + BLP;
  float* qc = m1sT + BLP;
  float* qs = qc + BLP;
  float* sg = qs + BLP;
  float* ctxsum = sg + B_ * L_;                     // B*128*256
  short* ctxbf = (short*)(ctxsum + B_ * 128 * 256);  // BLD shorts
  short* gvT = ctxbf + BLD;
  short* K2bf = gvT + BLD;
  short* SPbf = K2bf + B_ * L_ * 64;
  short* UT = SPbf + B_ * L_ * 64;                   // B*NC*256*64
  short* WAT = UT + (size_t)B_ * NC * 256 * 64;
  short* W1T = WAT + 384 * 256;
  short* WOT = W1T + 256 * 512;
  short* W2T = WOT + 256 * 256;
  short* W1OT = W2T + 32 * 256;

  wprep<<<1216, 256, 0, stream>>>(w_val, w_mem1v, w_off, w_key, w_gate, w_sk1,
                                  w_out, w_sk2, w_mem1o, WAT, W1T, WOT, W2T, W1OT);
  kernelA3G<<<512, 256, 0, stream>>>(x, pos, WAT, w_off, b_mem1v, b_off, b_key,
                                     b_gate, b_val, m1cT, m1sT, qc, qs, K2bf, gvT,
                                     sg, ctxsum);
  scan_all<<<772, 256, 0, stream>>>(m1cT, m1sT, sg, x, ctxsum, ctxbf);
  kernelCDg<<<256, 256, 0, stream>>>(x, ctxbf, W1T, b_sk1, W2T, b_sk2, gvT,
                                     SPbf, UT);
  kernelE<<<256, 256, 0, stream>>>(UT);
  kernelFGO<<<256, 256, 0, stream>>>(UT, SPbf, K2bf, gvT, sg, m1cT, m1sT, qc, qs,
                                     W1OT, b_mem1o, ln_g, ln_b, x, WOT, b_out,
                                     out);
}

// Round 12
// 205.978 us; speedup vs baseline: 1.0209x; 1.0209x over previous
//
#include <hip/hip_runtime.h>
#include <hip/hip_bf16.h>

constexpr int B_ = 4;
constexpr int L_ = 2048;
constexpr int D_ = 256;
constexpr int P_ = 32;
constexpr int CL = 32;
constexpr int NC = L_ / CL;  // 64

#define PI_F 3.14159265358979323846f
#define INV_SQRT_P 0.17677669529663687f

typedef __attribute__((ext_vector_type(8))) short short8_t;
typedef __attribute__((ext_vector_type(4))) float floatx4;

static __device__ inline short f2bf(float f) {
  unsigned int u;
  __builtin_memcpy(&u, &f, 4);
  unsigned int r = (u + 0x7fffu + ((u >> 16) & 1u)) >> 16;
  return (short)r;
}
static __device__ inline float bf2f(short s) {
  unsigned int u = ((unsigned int)(unsigned short)s) << 16;
  float f;
  __builtin_memcpy(&f, &u, 4);
  return f;
}

// A-fragment (lane holds A[m][k0..k0+7]) from fp32 row-major [m][256].
static __device__ inline short8_t loadAfragF32(const float* __restrict__ X,
                                               int row, int k0) {
  float4 v0 = *(const float4*)&X[row * 256 + k0];
  float4 v1 = *(const float4*)&X[row * 256 + k0 + 4];
  short s[8] = {f2bf(v0.x), f2bf(v0.y), f2bf(v0.z), f2bf(v0.w),
                f2bf(v1.x), f2bf(v1.y), f2bf(v1.z), f2bf(v1.w)};
  return *(short8_t*)s;
}

// ---------------- wprep: bf16 [n][k] weight transposes only ----------------
__global__ void wprep(const float* __restrict__ w_val, const float* __restrict__ w_mem1v,
                      const float* __restrict__ w_off, const float* __restrict__ w_key,
                      const float* __restrict__ w_gate, const float* __restrict__ w_sk1,
                      const float* __restrict__ w_out, const float* __restrict__ w_sk2,
                      const float* __restrict__ w_mem1o,
                      short* __restrict__ WAT, short* __restrict__ W1T,
                      short* __restrict__ WOT, short* __restrict__ W2T,
                      short* __restrict__ W1OT) {
  int blk = blockIdx.x, tid = threadIdx.x;
  if (blk < 384) {
    int idx = blk * 256 + tid;  // n*256 + k, n < 384
    int n = idx >> 8, k = idx & 255;
    float v;
    if (n < 256) v = w_val[k * 256 + n];
    else if (n < 288) v = w_mem1v[k * 32 + (n - 256)];
    else if (n < 320) v = w_off[k * 32 + (n - 288)];
    else if (n < 352) v = w_key[k * 32 + (n - 320)];
    else if (n == 352) v = w_gate[k];
    else v = 0.f;
    WAT[idx] = f2bf(v);
  } else if (blk < 896) {
    int idx = (blk - 384) * 256 + tid;  // n*512 + k
    int n = idx >> 9, k = idx & 511;
    W1T[idx] = f2bf(w_sk1[k * 256 + n]);
  } else if (blk < 1152) {
    int idx = (blk - 896) * 256 + tid;  // n*256 + k
    int n = idx >> 8, k = idx & 255;
    WOT[idx] = f2bf(w_out[k * 256 + n]);
  } else if (blk < 1184) {
    int idx = (blk - 1152) * 256 + tid;  // p*256 + k
    int p = idx >> 8, k = idx & 255;
    W2T[idx] = f2bf(w_sk2[k * 32 + p]);
  } else {
    int idx = (blk - 1184) * 256 + tid;  // d*32 + p
    int d = idx >> 5, p = idx & 31;
    W1OT[idx] = f2bf(w_mem1o[p * 256 + d]);
  }
}

// ---------------- Kernel A3G: gemm0 + phasor prep + ctx half-chunk sums ----
// 256 blocks x 512 threads (8 waves), 32 tokens/block. Y in LDS fp32 only.
__global__ __launch_bounds__(512) void kernelA3G(
    const float* __restrict__ x, const float* __restrict__ pos,
    const short* __restrict__ WAT, const float* __restrict__ w_off,
    const float* __restrict__ b_mem1v, const float* __restrict__ b_off,
    const float* __restrict__ b_key, const float* __restrict__ b_gate,
    const float* __restrict__ b_val,
    float* __restrict__ m1cT, float* __restrict__ m1sT,
    float* __restrict__ qc, float* __restrict__ qs,
    short* __restrict__ K2bf, short* __restrict__ gvT,
    float* __restrict__ sg, float* __restrict__ ctxsum) {
  __shared__ float Yl[32][390];  // ~49.9 KB
  __shared__ float gsh[32];
  int tid = threadIdx.x;
  int blk = blockIdx.x;
  int lbase = blk * 32;
  int b = lbase >> 11;
  int lane = tid & 63, w = tid >> 6;  // w in 0..7
  int ml = lane & 15, quad = lane >> 4, kq = quad * 8;

  // ---- Phase A: Y[32][384] = x @ WAT^T, wave w covers n in [w*48, w*48+48) --
  floatx4 acc[2][3] = {};
  const float* xrow = x + (size_t)lbase * 256;
  for (int ks = 0; ks < 8; ++ks) {
    int k0 = ks * 32 + kq;
    short8_t a0 = loadAfragF32(xrow, ml, k0);
    short8_t a1 = loadAfragF32(xrow, 16 + ml, k0);
#pragma unroll
    for (int nt = 0; nt < 3; ++nt) {
      int n = w * 48 + nt * 16;
      short8_t bfr = *(const short8_t*)&WAT[(n + ml) * 256 + k0];
      acc[0][nt] = __builtin_amdgcn_mfma_f32_16x16x32_bf16(a0, bfr, acc[0][nt], 0, 0, 0);
      acc[1][nt] = __builtin_amdgcn_mfma_f32_16x16x32_bf16(a1, bfr, acc[1][nt], 0, 0, 0);
    }
  }
#pragma unroll
  for (int nt = 0; nt < 3; ++nt) {
    int n = w * 48 + nt * 16;
#pragma unroll
    for (int mt = 0; mt < 2; ++mt)
#pragma unroll
      for (int r = 0; r < 4; ++r)
        Yl[mt * 16 + quad * 4 + r][n + ml] = acc[mt][nt][r];
  }
  __syncthreads();

  // ---- Phase B: per-(t,p) phasor prep (1024 pairs / 512 threads) ----
  for (int h = 0; h < 2; ++h) {
    int t = h * 16 + (tid >> 5), p = tid & 31;
    int tok = lbase + t, l = tok & (L_ - 1);
    float gate = 1.f / (1.f + expf(-(Yl[t][352] + b_gate[0])));
    if (p == 0) {
      sg[tok] = gate;
      gsh[t] = gate;
    }
    float v1 = Yl[t][256 + p] + b_mem1v[p];
    float ph = pos[l * 32 + p];
    float pc = cosf(ph), ps = sinf(ph);
    m1cT[(b * 32 + p) * L_ + l] = pc * v1;
    m1sT[(b * 32 + p) * L_ + l] = ps * v1;
    float a = b_off[p];
    for (int j = 0; j < 32; ++j) a += pos[l * 32 + j] * w_off[(256 + j) * 32 + p];
    float off = tanhf(Yl[t][288 + p] + a) * PI_F;
    float oc = cosf(off), os = sinf(off);
    int idx = tok * 32 + p;
    qc[idx] = pc * oc - ps * os;
    qs[idx] = ps * oc + pc * os;
    float kp = tanhf(Yl[t][320 + p] + b_key[p]) * PI_F;
    K2bf[tok * 64 + p] = f2bf(cosf(kp));
    K2bf[tok * 64 + 32 + p] = f2bf(sinf(kp));
  }
  __syncthreads();

  // ---- Phase C: gvT (bf16, [d][t]) + ctx half-chunk sums ----
  {
    int d = tid & 255, th = tid >> 8;  // th in 0..1
    float bv = b_val[d];
    float cs = 0.f;
    short sv[16];
#pragma unroll 8
    for (int i = 0; i < 16; ++i) {
      int t = th * 16 + i;
      cs += x[(size_t)(lbase + t) * 256 + d];
      sv[i] = f2bf((Yl[t][d] + bv) * gsh[t]);
    }
    int hc = ((lbase & (L_ - 1)) >> 4) + th;
    ctxsum[(b * 128 + hc) * 256 + d] = cs;
    int bc = lbase >> 5;
    int gb = (bc * 256 + d) * 32 + th * 16;
    *(short8_t*)&gvT[gb] = *(short8_t*)&sv[0];
    *(short8_t*)&gvT[gb + 8] = *(short8_t*)&sv[8];
  }
}

// ---------------- scan_all: m1/sg scans + ctx local scan -------------------
// blk<256: m1 rows; 256..259: sg; 260..771: ctx half-chunk local scan.
__global__ void scan_all(float* __restrict__ m1cT, float* __restrict__ m1sT,
                         float* __restrict__ sg, const float* __restrict__ x,
                         const float* __restrict__ ctxsum, short* __restrict__ ctxbf) {
  int blk = blockIdx.x;
  int tid = threadIdx.x;
  if (blk >= 260) {
    int c2 = blk - 260;
    int b = c2 >> 7, hc = c2 & 127;
    float run = 0.f;
    int sb = b * 128 * 256 + tid;
    for (int c = 0; c < hc; ++c) run += ctxsum[sb + c * 256];
    int xb = (b * L_ + hc * 16) * 256 + tid;
#pragma unroll 8
    for (int i = 0; i < 16; ++i) {
      run += x[xb + i * 256];
      int l = hc * 16 + i;
      ctxbf[xb + i * 256] = f2bf(run / (float)(l + 1));
    }
    return;
  }
  int lane = tid & 63, wid = tid >> 6;
  __shared__ float wsum[4];
  float carry = 0.f;
  float* arr;
  int base;
  if (blk < 256) {
    arr = (blk < 128) ? m1cT : m1sT;
    base = (blk & 127) * L_;
  } else {
    arr = sg;
    base = (blk - 256) * L_;
  }
  for (int t0 = 0; t0 < L_; t0 += 256) {
    int l = t0 + tid;
    float v = arr[base + l];
#pragma unroll
    for (int off = 1; off < 64; off <<= 1) {
      float n = __shfl_up(v, off, 64);
      if (lane >= off) v += n;
    }
    if (lane == 63) wsum[wid] = v;
    __syncthreads();
    float add = carry;
    for (int w = 0; w < wid; ++w) add += wsum[w];
    arr[base + l] = v + add;
    carry += wsum[0] + wsum[1] + wsum[2] + wsum[3];
    __syncthreads();
  }
}

// ---------------- Kernel CDg: gemm1 (sk1) + sk2 phases + chunk U sums ------
// 256 blocks x 512 threads (8 waves), 32 tokens/chunk.
__global__ __launch_bounds__(512) void kernelCDg(
    const float* __restrict__ x, const short* __restrict__ ctxbf,
    const short* __restrict__ W1T, const float* __restrict__ b_sk1,
    const short* __restrict__ W2T, const float* __restrict__ b_sk2,
    const short* __restrict__ gvT, short* __restrict__ SPbf,
    short* __restrict__ UT) {
  __shared__ __align__(16) short hsl[32][264];
  __shared__ __align__(16) short SPL[64][40];
  int tid = threadIdx.x;
  int bc = blockIdx.x;
  int lbase = bc * 32;
  int lane = tid & 63, w = tid >> 6;  // 0..7
  int ml = lane & 15, quad = lane >> 4, kq = quad * 8;

  // ---- Phase 1: hs = gelu([x|ctx] @ w_sk1 + b_sk1), wave w: n in [w*32,+32)
  floatx4 acc[2][2] = {};
  const float* xrow = x + (size_t)lbase * 256;
  for (int ks = 0; ks < 16; ++ks) {
    int k0 = ks * 32 + kq;
    short8_t a0, a1;
    if (ks < 8) {
      a0 = loadAfragF32(xrow, ml, k0);
      a1 = loadAfragF32(xrow, 16 + ml, k0);
    } else {
      a0 = *(const short8_t*)&ctxbf[(size_t)(lbase + ml) * 256 + (k0 - 256)];
      a1 = *(const short8_t*)&ctxbf[(size_t)(lbase + 16 + ml) * 256 + (k0 - 256)];
    }
#pragma unroll
    for (int nt = 0; nt < 2; ++nt) {
      short8_t bfr = *(const short8_t*)&W1T[(w * 32 + nt * 16 + ml) * 512 + k0];
      acc[0][nt] = __builtin_amdgcn_mfma_f32_16x16x32_bf16(a0, bfr, acc[0][nt], 0, 0, 0);
      acc[1][nt] = __builtin_amdgcn_mfma_f32_16x16x32_bf16(a1, bfr, acc[1][nt], 0, 0, 0);
    }
  }
#pragma unroll
  for (int nt = 0; nt < 2; ++nt) {
    int n = w * 32 + nt * 16 + ml;
    float bs = b_sk1[n];
#pragma unroll
    for (int mt = 0; mt < 2; ++mt)
#pragma unroll
      for (int r = 0; r < 4; ++r) {
        float v = acc[mt][nt][r] + bs;
        float g = 0.5f * v * (1.f + erff(v * 0.70710678118654752f));
        hsl[mt * 16 + quad * 4 + r][n] = f2bf(g);
      }
  }
  __syncthreads();

  // ---- Phase 2: storage phases (sk2), waves 0..3 only ----
  if (w < 4) {
    int m0 = (w & 1) * 16, n0 = (w >> 1) * 16;
    floatx4 pacc = {};
#pragma unroll
    for (int ks = 0; ks < 8; ++ks) {
      int k0 = ks * 32 + kq;
      short8_t a = *(short8_t*)&hsl[m0 + ml][k0];
      short8_t bfr = *(const short8_t*)&W2T[(n0 + ml) * 256 + k0];
      pacc = __builtin_amdgcn_mfma_f32_16x16x32_bf16(a, bfr, pacc, 0, 0, 0);
    }
    int p = n0 + ml;
    float bs = b_sk2[p];
#pragma unroll
    for (int r = 0; r < 4; ++r) {
      int tl = m0 + quad * 4 + r;
      int tok = lbase + tl;
      float sp = tanhf(pacc[r] + bs) * PI_F;
      short c = f2bf(cosf(sp)), s = f2bf(sinf(sp));
      SPL[p][tl] = c;
      SPL[32 + p][tl] = s;
      SPbf[tok * 64 + p] = c;
      SPbf[tok * 64 + 32 + p] = s;
    }
  }
  __syncthreads();

  // ---- Phase 3: U_chunk[64 q][256 d] = SPL @ gv, wave w: d in [w*32,+32) --
  short8_t a[4];
#pragma unroll
  for (int mt = 0; mt < 4; ++mt) a[mt] = *(short8_t*)&SPL[mt * 16 + ml][kq];
  floatx4 uacc[4][2] = {};
#pragma unroll
  for (int nt = 0; nt < 2; ++nt) {
    short8_t bfr = *(const short8_t*)&gvT[(bc * 256 + w * 32 + nt * 16 + ml) * 32 + kq];
#pragma unroll
    for (int mt = 0; mt < 4; ++mt)
      uacc[mt][nt] = __builtin_amdgcn_mfma_f32_16x16x32_bf16(a[mt], bfr, uacc[mt][nt], 0, 0, 0);
  }
#pragma unroll
  for (int mt = 0; mt < 4; ++mt)
#pragma unroll
    for (int nt = 0; nt < 2; ++nt)
#pragma unroll
      for (int r = 0; r < 4; ++r) {
        int q = mt * 16 + quad * 4 + r;
        int d = w * 32 + nt * 16 + ml;
        UT[(bc * 256 + d) * 64 + q] = f2bf(uacc[mt][nt][r]);
      }
}

// ---------------- Kernel E: exclusive chunk prefix over UT (bf16) ----------
__global__ void kernelE(short* __restrict__ UT) {
  int gt = blockIdx.x * 256 + threadIdx.x;  // B*256d*64q = 65536
  int q = gt & 63;
  int d = (gt >> 6) & 255;
  int b = gt >> 14;
  int base = ((b * NC) * 256 + d) * 64 + q;
  const int cs = 256 * 64;
  float run = 0.f;
  for (int c0 = 0; c0 < NC; c0 += 8) {
    short v[8];
#pragma unroll
    for (int j = 0; j < 8; ++j) v[j] = UT[base + (c0 + j) * cs];
#pragma unroll
    for (int j = 0; j < 8; ++j) {
      UT[base + (c0 + j) * cs] = f2bf(run);
      run += bf2f(v[j]);
    }
  }
}

// ---------------- Kernel FGO: retrieval + pos_out + LN + output GEMM -------
// 256 blocks x 512 threads (8 waves).
__global__ __launch_bounds__(512) void kernelFGO(
    const short* __restrict__ UT, const short* __restrict__ SPbf,
    const short* __restrict__ K2bf, const short* __restrict__ gvT,
    const float* __restrict__ sgc, const float* __restrict__ m1cT,
    const float* __restrict__ m1sT, const float* __restrict__ qc,
    const float* __restrict__ qs, const short* __restrict__ W1OT,
    const float* __restrict__ b_mem1o, const float* __restrict__ ln_g,
    const float* __restrict__ ln_b, const float* __restrict__ x,
    const short* __restrict__ WOT, const float* __restrict__ b_out,
    float* __restrict__ out) {
  __shared__ __align__(16) short SL[32][40];
  __shared__ __align__(16) short PR[32][40];
  __shared__ float CMB[32][260];
  __shared__ __align__(16) short CBN[32][264];
  __shared__ float scl[32], mu_s[32], rs_s[32];
  int tid = threadIdx.x;
  int bc = blockIdx.x;
  int lbase = bc * CL;
  int bb = bc >> 6, lloc = (bc & 63) * 32;
  int lane = tid & 63, w = tid >> 6;  // 0..7
  int ml = lane & 15, quad = lane >> 4, kq = quad * 8;
  if (tid < 32) scl[tid] = rsqrtf(fmaxf(sgc[lbase + tid], 1.f)) * INV_SQRT_P;
  for (int it = 0; it < 2; ++it) {
    int i = it * 512 + tid;
    int p = i >> 5, t = i & 31;
    int gT = (bb * 32 + p) * L_ + lloc + t;
    int g = (lbase + t) * 32 + p;
    PR[t][p] = f2bf((m1cT[gT] * qc[g] + m1sT[gT] * qs[g]) * INV_SQRT_P);
  }
  floatx4 acc[2][2] = {};
  short8_t ka0 = *(const short8_t*)&K2bf[(lbase + ml) * 64 + kq];
  short8_t ka1 = *(const short8_t*)&K2bf[(lbase + 16 + ml) * 64 + kq];
  short8_t kb0 = *(const short8_t*)&K2bf[(lbase + ml) * 64 + 32 + kq];
  short8_t kb1 = *(const short8_t*)&K2bf[(lbase + 16 + ml) * 64 + 32 + kq];
#pragma unroll
  for (int nt = 0; nt < 2; ++nt) {
    short8_t b = *(const short8_t*)&UT[(bc * 256 + w * 32 + nt * 16 + ml) * 64 + kq];
    acc[0][nt] = __builtin_amdgcn_mfma_f32_16x16x32_bf16(ka0, b, acc[0][nt], 0, 0, 0);
    acc[1][nt] = __builtin_amdgcn_mfma_f32_16x16x32_bf16(ka1, b, acc[1][nt], 0, 0, 0);
  }
  if (w == 0) {
    floatx4 sacc[2][2] = {};
#pragma unroll
    for (int ks2 = 0; ks2 < 2; ++ks2) {
      short8_t a0 = (ks2 == 0) ? ka0 : kb0;
      short8_t a1 = (ks2 == 0) ? ka1 : kb1;
      short8_t b0 = *(const short8_t*)&SPbf[(lbase + ml) * 64 + ks2 * 32 + kq];
      short8_t b1 = *(const short8_t*)&SPbf[(lbase + 16 + ml) * 64 + ks2 * 32 + kq];
      sacc[0][0] = __builtin_amdgcn_mfma_f32_16x16x32_bf16(a0, b0, sacc[0][0], 0, 0, 0);
      sacc[0][1] = __builtin_amdgcn_mfma_f32_16x16x32_bf16(a0, b1, sacc[0][1], 0, 0, 0);
      sacc[1][0] = __builtin_amdgcn_mfma_f32_16x16x32_bf16(a1, b0, sacc[1][0], 0, 0, 0);
      sacc[1][1] = __builtin_amdgcn_mfma_f32_16x16x32_bf16(a1, b1, sacc[1][1], 0, 0, 0);
    }
#pragma unroll
    for (int mt = 0; mt < 2; ++mt)
#pragma unroll
      for (int nt = 0; nt < 2; ++nt)
#pragma unroll
        for (int r = 0; r < 4; ++r) {
          int trow = mt * 16 + quad * 4 + r;
          int scol = nt * 16 + ml;
          float v = (scol <= trow) ? sacc[mt][nt][r] : 0.f;
          SL[trow][scol] = f2bf(v);
        }
  }
  __syncthreads();
#pragma unroll
  for (int nt = 0; nt < 2; ++nt) {
    short8_t b = *(const short8_t*)&UT[(bc * 256 + w * 32 + nt * 16 + ml) * 64 + 32 + kq];
    acc[0][nt] = __builtin_amdgcn_mfma_f32_16x16x32_bf16(kb0, b, acc[0][nt], 0, 0, 0);
    acc[1][nt] = __builtin_amdgcn_mfma_f32_16x16x32_bf16(kb1, b, acc[1][nt], 0, 0, 0);
  }
  {
    short8_t a0 = *(short8_t*)&SL[ml][kq];
    short8_t a1 = *(short8_t*)&SL[16 + ml][kq];
#pragma unroll
    for (int nt = 0; nt < 2; ++nt) {
      short8_t b = *(const short8_t*)&gvT[(bc * 256 + w * 32 + nt * 16 + ml) * 32 + kq];
      acc[0][nt] = __builtin_amdgcn_mfma_f32_16x16x32_bf16(a0, b, acc[0][nt], 0, 0, 0);
      acc[1][nt] = __builtin_amdgcn_mfma_f32_16x16x32_bf16(a1, b, acc[1][nt], 0, 0, 0);
    }
  }
  floatx4 macc[2][2] = {};
  {
    short8_t a0 = *(short8_t*)&PR[ml][kq];
    short8_t a1 = *(short8_t*)&PR[16 + ml][kq];
#pragma unroll
    for (int nt = 0; nt < 2; ++nt) {
      short8_t b = *(const short8_t*)&W1OT[(w * 32 + nt * 16 + ml) * 32 + kq];
      macc[0][nt] = __builtin_amdgcn_mfma_f32_16x16x32_bf16(a0, b, macc[0][nt], 0, 0, 0);
      macc[1][nt] = __builtin_amdgcn_mfma_f32_16x16x32_bf16(a1, b, macc[1][nt], 0, 0, 0);
    }
  }
#pragma unroll
  for (int mt = 0; mt < 2; ++mt)
#pragma unroll
    for (int nt = 0; nt < 2; ++nt) {
      int d = w * 32 + nt * 16 + ml;
      float bm = b_mem1o[d];
#pragma unroll
      for (int r = 0; r < 4; ++r) {
        int t = mt * 16 + quad * 4 + r;
        CMB[t][d] = acc[mt][nt][r] * scl[t] + macc[mt][nt][r] + bm;
      }
    }
  __syncthreads();
  {
    int t = tid >> 4, g = tid & 15;  // 32 tokens x 16 groups
    float s = 0.f, s2 = 0.f;
#pragma unroll
    for (int j = 0; j < 16; ++j) {
      float v = CMB[t][g + j * 16];
      s += v;
      s2 += v * v;
    }
#pragma unroll
    for (int m = 1; m < 16; m <<= 1) {
      s += __shfl_xor(s, m, 64);
      s2 += __shfl_xor(s2, m, 64);
    }
    if (g == 0) {
      float mu = s / (float)D_;
      float var = s2 / (float)D_ - mu * mu;
      mu_s[t] = mu;
      rs_s[t] = rsqrtf(var + 1e-5f);
    }
  }
  __syncthreads();
  {
    int d = tid & 255, th = tid >> 8;
    float lg = ln_g[d], lb = ln_b[d];
#pragma unroll
    for (int i = 0; i < 16; ++i) {
      int t = th * 16 + i;
      CBN[t][d] = f2bf((CMB[t][d] - mu_s[t]) * rs_s[t] * lg + lb);
    }
  }
  __syncthreads();
  // ---- output GEMM: out = x + CBN @ w_out + b_out, wave w: n in [w*32,+32)
  floatx4 oacc[2][2] = {};
  for (int ks = 0; ks < 8; ++ks) {
    int k0 = ks * 32 + kq;
    short8_t a0 = *(short8_t*)&CBN[ml][k0];
    short8_t a1 = *(short8_t*)&CBN[16 + ml][k0];
#pragma unroll
    for (int nt = 0; nt < 2; ++nt) {
      short8_t b = *(const short8_t*)&WOT[(w * 32 + nt * 16 + ml) * 256 + k0];
      oacc[0][nt] = __builtin_amdgcn_mfma_f32_16x16x32_bf16(a0, b, oacc[0][nt], 0, 0, 0);
      oacc[1][nt] = __builtin_amdgcn_mfma_f32_16x16x32_bf16(a1, b, oacc[1][nt], 0, 0, 0);
    }
  }
#pragma unroll
  for (int nt = 0; nt < 2; ++nt) {
    int n = w * 32 + nt * 16 + ml;
    float bo = b_out[n];
#pragma unroll
    for (int mt = 0; mt < 2; ++mt)
#pragma unroll
      for (int r = 0; r < 4; ++r) {
        int tok = lbase + mt * 16 + quad * 4 + r;
        out[(size_t)tok * 256 + n] = x[(size_t)tok * 256 + n] + oacc[mt][nt][r] + bo;
      }
  }
}

extern "C" void kernel_launch(void* const* d_in, const int* in_sizes, int n_in,
                              void* d_out, int out_size, void* d_ws, size_t ws_size,
                              hipStream_t stream) {
  const float* x = (const float*)d_in[0];
  const float* pos = (const float*)d_in[1];
  const float* w_mem1v = (const float*)d_in[2];
  const float* b_mem1v = (const float*)d_in[3];
  const float* w_mem1o = (const float*)d_in[4];
  const float* b_mem1o = (const float*)d_in[5];
  const float* w_off = (const float*)d_in[6];
  const float* b_off = (const float*)d_in[7];
  const float* w_key = (const float*)d_in[8];
  const float* b_key = (const float*)d_in[9];
  const float* w_val = (const float*)d_in[10];
  const float* b_val = (const float*)d_in[11];
  const float* w_sk1 = (const float*)d_in[12];
  const float* b_sk1 = (const float*)d_in[13];
  const float* w_sk2 = (const float*)d_in[14];
  const float* b_sk2 = (const float*)d_in[15];
  const float* w_gate = (const float*)d_in[16];
  const float* b_gate = (const float*)d_in[17];
  const float* ln_g = (const float*)d_in[18];
  const float* ln_b = (const float*)d_in[19];
  const float* w_out = (const float*)d_in[20];
  const float* b_out = (const float*)d_in[21];
  float* out = (float*)d_out;
  float* ws = (float*)d_ws;

  const int BLP = B_ * L_ * P_;  // 262144
  const int BLD = B_ * L_ * D_;  // 2097152
  float* m1cT = ws;
  float* m1sT = m1cT + BLP;
  float* qc = m1sT + BLP;
  float* qs = qc + BLP;
  float* sg = qs + BLP;
  float* ctxsum = sg + B_ * L_;                      // B*128*256
  short* ctxbf = (short*)(ctxsum + B_ * 128 * 256);  // BLD shorts
  short* gvT = ctxbf + BLD;
  short* K2bf = gvT + BLD;
  short* SPbf = K2bf + B_ * L_ * 64;
  short* UT = SPbf + B_ * L_ * 64;                   // B*NC*256*64
  short* WAT = UT + (size_t)B_ * NC * 256 * 64;
  short* W1T = WAT + 384 * 256;
  short* WOT = W1T + 256 * 512;
  short* W2T = WOT + 256 * 256;
  short* W1OT = W2T + 32 * 256;

  wprep<<<1216, 256, 0, stream>>>(w_val, w_mem1v, w_off, w_key, w_gate, w_sk1,
                                  w_out, w_sk2, w_mem1o, WAT, W1T, WOT, W2T, W1OT);
  kernelA3G<<<256, 512, 0, stream>>>(x, pos, WAT, w_off, b_mem1v, b_off, b_key,
                                     b_gate, b_val, m1cT, m1sT, qc, qs, K2bf, gvT,
                                     sg, ctxsum);
  scan_all<<<772, 256, 0, stream>>>(m1cT, m1sT, sg, x, ctxsum, ctxbf);
  kernelCDg<<<256, 512, 0, stream>>>(x, ctxbf, W1T, b_sk1, W2T, b_sk2, gvT,
                                     SPbf, UT);
  kernelE<<<256, 256, 0, stream>>>(UT);
  kernelFGO<<<256, 512, 0, stream>>>(UT, SPbf, K2bf, gvT, sg, m1cT, m1sT, qc, qs,
                                     W1OT, b_mem1o, ln_g, ln_b, x, WOT, b_out,
                                     out);
}